// Round 5
// baseline (2857.233 us; speedup 1.0000x reference)
//
#include <hip/hip_runtime.h>

// Problem constants
#define B_TOT   4096          // 4*1024 batch rows
#define D_IN    2048
#define D_OUT   2048
#define LIN     512
#define LOUT    512
#define CORE_R_STRIDE 2097152 // LOUT*LIN*RK elements
#define CORE_O_STRIDE 4096    // LIN*RK elements

// Workspace layout (float offsets) — 42.5 MB total, same as the passing R3 run
#define WS_XT    0                            // xT [2048][4096]
#define WS_GHAT  8388608                      // Ghat [4][8][512][8]
#define WS_S     (8388608 + 131072)           // S    [4][4096][64]
#define WS_ENVT  (8388608 + 131072 + 1048576) // envT [4][64][4096]

typedef __attribute__((ext_vector_type(8))) __bf16 bf16x8;
typedef __attribute__((ext_vector_type(4))) float f32x4;
typedef __attribute__((ext_vector_type(4))) unsigned int u32x4;

// ---------------- Kernel 1: transpose x [4096][2048] -> xT [2048][4096] --------
__global__ __launch_bounds__(256) void k_transpose(const float* __restrict__ x,
                                                   float* __restrict__ xT) {
    __shared__ float tile[32][33];
    int b0 = blockIdx.x * 32;
    int c0 = blockIdx.y * 32;
    int tx = threadIdx.x;
    int ty = threadIdx.y;
#pragma unroll
    for (int j = 0; j < 4; ++j)
        tile[ty + j * 8][tx] = x[(size_t)(b0 + ty + j * 8) * D_IN + c0 + tx];
    __syncthreads();
#pragma unroll
    for (int j = 0; j < 4; ++j)
        xT[(size_t)(c0 + ty + j * 8) * B_TOT + b0 + tx] = tile[tx][ty + j * 8];
}

// ---------------- Kernel 2: Ghat[i][r][xs] = sum_o G_i[r][o][xs] (fp32 G) ------
__global__ __launch_bounds__(256) void k_reduce_g(const float* __restrict__ g0,
                                                  const float* __restrict__ g1,
                                                  const float* __restrict__ g2,
                                                  const float* __restrict__ g3,
                                                  float* __restrict__ ghat) {
    int i = blockIdx.z;
    int r = blockIdx.y;
    int xs = blockIdx.x * 256 + threadIdx.x;
    const float* G = (i == 0) ? g0 : (i == 1) ? g1 : (i == 2) ? g2 : g3;
    const float* base = G + (size_t)r * CORE_R_STRIDE + xs;
    float acc = 0.f;
#pragma unroll 8
    for (int o = 0; o < LOUT; ++o) acc += base[(size_t)o * CORE_O_STRIDE];
    ghat[(size_t)i * 32768 + r * 4096 + xs] = acc;
}

// ---------------- Kernel 3: S[i][b][r*8+s] = sum_x Ghat[i][r][x][s]*x[b][i*512+x]
__global__ __launch_bounds__(256) void k_s(const float* __restrict__ x,
                                           const float* __restrict__ ghat,
                                           float* __restrict__ S) {
    int i = blockIdx.y;
    int tid = threadIdx.x;
    int rs = tid & 63;
    int b = blockIdx.x * 4 + (tid >> 6);
    int r = rs >> 3, s = rs & 7;
    const float* gh = ghat + (size_t)i * 32768 + r * 4096 + s;
    const float* xr = x + (size_t)b * D_IN + i * LIN;
    float acc = 0.f;
#pragma unroll 8
    for (int xi = 0; xi < LIN; ++xi) acc = fmaf(gh[xi * 8], xr[xi], acc);
    S[(size_t)i * (B_TOT * 64) + b * 64 + rs] = acc;
}

// ---------------- Kernel 4: chain products -> envT ----------------------------
__device__ __forceinline__ float mm8(float A, float B, int lane) {
    float c = 0.f;
#pragma unroll
    for (int p = 0; p < 8; ++p) {
        float a = __shfl(A, (lane & 56) | p, 64);
        float b = __shfl(B, (p << 3) | (lane & 7), 64);
        c = fmaf(a, b, c);
    }
    return c;
}
__device__ __forceinline__ float tr8(float E, int lane) {
    return __shfl(E, ((lane & 7) << 3) | (lane >> 3), 64);
}

__global__ __launch_bounds__(256) void k_env(const float* __restrict__ S,
                                             float* __restrict__ envT) {
    int tid = threadIdx.x;
    int lane = tid & 63;
    int b = blockIdx.x * 4 + (tid >> 6);
    float S0 = S[0 * (B_TOT * 64) + b * 64 + lane];
    float S1 = S[1 * (B_TOT * 64) + b * 64 + lane];
    float S2 = S[2 * (B_TOT * 64) + b * 64 + lane];
    float S3 = S[3 * (B_TOT * 64) + b * 64 + lane];

    float P1 = S0;
    float P2 = mm8(P1, S1, lane);
    float P3 = mm8(P2, S2, lane);
    float Q2 = S3;
    float Q1 = mm8(S2, Q2, lane);
    float Q0 = mm8(S1, Q1, lane);

    float e0 = tr8(Q0, lane);
    float e1 = tr8(mm8(Q1, P1, lane), lane);
    float e2 = tr8(mm8(Q2, P2, lane), lane);
    float e3 = tr8(P3, lane);

    envT[(size_t)(0 * 64 + lane) * B_TOT + b] = e0;
    envT[(size_t)(1 * 64 + lane) * B_TOT + b] = e1;
    envT[(size_t)(2 * 64 + lane) * B_TOT + b] = e2;
    envT[(size_t)(3 * 64 + lane) * B_TOT + b] = e3;
}

// ---------------- split helper ------------------------------------------------
// hi = truncate-to-bf16(v); lo = truncate-to-bf16(v - hi). Returns {hi2, lo2}.
// Packed little-endian: low short = first element.
__device__ __forceinline__ uint2 split2(float a, float b) {
    unsigned int ua = __float_as_uint(a), ub = __float_as_uint(b);
    unsigned int h = (ub & 0xffff0000u) | (ua >> 16);
    float la = a - __uint_as_float(ua & 0xffff0000u);
    float lb = b - __uint_as_float(ub & 0xffff0000u);
    unsigned int l = (__float_as_uint(lb) & 0xffff0000u) | (__float_as_uint(la) >> 16);
    return make_uint2(h, l);
}

// ---------------- Kernel 4.5: IN-PLACE split of G into bf16 hi/lo --------------
// Each thread owns one aligned 8-element (32 B) chunk: reads 8 fp32, writes back
// [hi x8 (16B)][lo x8 (16B)] to the SAME addresses. Race-free; harness restores
// pristine fp32 G before every launch. Must run AFTER k_reduce_g (fp32 reader).
__global__ __launch_bounds__(256) void k_split_inplace(float* __restrict__ g0,
                                                       float* __restrict__ g1,
                                                       float* __restrict__ g2,
                                                       float* __restrict__ g3) {
    float* G = (blockIdx.y == 0) ? g0 : (blockIdx.y == 1) ? g1
             : (blockIdx.y == 2) ? g2 : g3;
    size_t idx = ((size_t)blockIdx.x * 256 + threadIdx.x) * 8;
    float4 f0 = *(const float4*)&G[idx];
    float4 f1 = *(const float4*)&G[idx + 4];
    u32x4 H, L;
    uint2 p;
    p = split2(f0.x, f0.y); H.x = p.x; L.x = p.y;
    p = split2(f0.z, f0.w); H.y = p.x; L.y = p.y;
    p = split2(f1.x, f1.y); H.z = p.x; L.z = p.y;
    p = split2(f1.z, f1.w); H.w = p.x; L.w = p.y;
    *(u32x4*)&G[idx] = H;
    *(u32x4*)&G[idx + 4] = L;
}

// ---------------- Kernel 5: MFMA GEMM out_i = sum_r Z_{i,r} @ G_{i,r}^T --------
// Z (=env*x, split-bf16) built cooperatively in LDS once per block-kk;
// B staged from the in-place-split G by pure 64 B/thread copy (no VALU split).
// LDS rows: 128 B = [hi k0-7][lo k0-7][hi k8-15][lo k8-15][hi k16-23][lo k16-23]
//                   [hi k24-31][lo k24-31]  (Z uses [hi k0-31][lo k0-31] halves)
#define LROW 64   // shorts per LDS row (128 B)
__global__ __launch_bounds__(256, 2) void k_gemm_mfma(const unsigned char* __restrict__ gs0,
                                                      const unsigned char* __restrict__ gs1,
                                                      const unsigned char* __restrict__ gs2,
                                                      const unsigned char* __restrict__ gs3,
                                                      const float* __restrict__ xT,
                                                      const float* __restrict__ envT,
                                                      const float* __restrict__ bias,
                                                      float* __restrict__ out) {
    int l = blockIdx.x;                       // 0..511
    int c = (l & 7) | (((l >> 3) >> 5) << 3); // combo 0..15; 32 b-blocks of one
    int b_idx = (l >> 3) & 31;                // combo land on one XCD (l%8 const)
    int i = c >> 2;
    int o0 = (c & 3) * 128;
    int b0 = b_idx * 128;

    const unsigned char* G = (i == 0) ? gs0 : (i == 1) ? gs1 : (i == 2) ? gs2 : gs3;
    const float* xTi = xT + (size_t)i * LIN * B_TOT;
    const float* eTi = envT + (size_t)i * 64 * B_TOT;

    __shared__ __align__(16) short Zs[128 * LROW];
    __shared__ __align__(16) short Bs[128 * LROW];

    const int tid = threadIdx.x;
    const int lane = tid & 63;
    const int wave = tid >> 6;
    const int wm = (wave >> 1) * 64;
    const int wn = (wave & 1) * 64;
    const int l15 = lane & 15;
    const int quad = lane >> 4;

    // Z-gen role: thread -> (m-row zm, k-half zh)
    const int zm = tid >> 1;
    const int zh = tid & 1;
    // B-stage role: thread -> (o-row brow, 64B-half bhalf)
    const int brow = tid >> 1;
    const int bhalf = tid & 1;

    f32x4 acc[4][4];
#pragma unroll
    for (int mf = 0; mf < 4; ++mf)
#pragma unroll
        for (int nf = 0; nf < 4; ++nf) acc[mf][nf] = (f32x4){0.f, 0.f, 0.f, 0.f};

    for (int r = 0; r < 8; ++r) {
        // env values for the Z-gen role (one m-row per thread)
        float e[8];
#pragma unroll
        for (int s = 0; s < 8; ++s)
            e[s] = eTi[(size_t)(r * 8 + s) * B_TOT + b0 + zm];

        // split-G slab for this (r, o-row): row stride = 16 KB (4096 elem * 4 B)
        const unsigned char* gsrc = G
            + ((size_t)r * CORE_R_STRIDE + (size_t)(o0 + brow) * CORE_O_STRIDE) * 4
            + bhalf * 64;

        for (int kk = 0; kk < 128; ++kk) {
            __syncthreads();
            // ---- Z-gen: z[k] = e[k&7] * x[kk*4 + (k>>3)], k in [zh*16, zh*16+16)
            {
                float x0 = xTi[(size_t)(kk * 4 + zh * 2 + 0) * B_TOT + b0 + zm];
                float x1 = xTi[(size_t)(kk * 4 + zh * 2 + 1) * B_TOT + b0 + zm];
                u32x4 H0, L0, H1, L1;
                uint2 p;
                p = split2(e[0] * x0, e[1] * x0); H0.x = p.x; L0.x = p.y;
                p = split2(e[2] * x0, e[3] * x0); H0.y = p.x; L0.y = p.y;
                p = split2(e[4] * x0, e[5] * x0); H0.z = p.x; L0.z = p.y;
                p = split2(e[6] * x0, e[7] * x0); H0.w = p.x; L0.w = p.y;
                p = split2(e[0] * x1, e[1] * x1); H1.x = p.x; L1.x = p.y;
                p = split2(e[2] * x1, e[3] * x1); H1.y = p.x; L1.y = p.y;
                p = split2(e[4] * x1, e[5] * x1); H1.z = p.x; L1.z = p.y;
                p = split2(e[6] * x1, e[7] * x1); H1.w = p.x; L1.w = p.y;
                short* zrow = Zs + zm * LROW;
                *(u32x4*)(zrow + zh * 16) = H0;
                *(u32x4*)(zrow + zh * 16 + 8) = H1;
                *(u32x4*)(zrow + 32 + zh * 16) = L0;
                *(u32x4*)(zrow + 32 + zh * 16 + 8) = L1;
            }
            // ---- B-stage: pure copy, 64 B/thread, already in frag format ----
            {
                const unsigned char* src = gsrc + (size_t)kk * 128;
                short* dstrow = Bs + brow * LROW + bhalf * 32;
#pragma unroll
                for (int cc = 0; cc < 4; ++cc)
                    *(u32x4*)(dstrow + cc * 8) = *(const u32x4*)(src + cc * 16);
            }
            __syncthreads();

            // ---- fragments ----
            bf16x8 ah[4], al[4], bh[4], bl[4];
#pragma unroll
            for (int mf = 0; mf < 4; ++mf) {
                int m = wm + mf * 16 + l15;
                ah[mf] = *(const bf16x8*)(Zs + m * LROW + quad * 8);
                al[mf] = *(const bf16x8*)(Zs + m * LROW + 32 + quad * 8);
            }
#pragma unroll
            for (int nf = 0; nf < 4; ++nf) {
                int n = wn + nf * 16 + l15;
                bh[nf] = *(const bf16x8*)(Bs + n * LROW + quad * 16);
                bl[nf] = *(const bf16x8*)(Bs + n * LROW + quad * 16 + 8);
            }
#pragma unroll
            for (int mf = 0; mf < 4; ++mf) {
#pragma unroll
                for (int nf = 0; nf < 4; ++nf) {
                    acc[mf][nf] = __builtin_amdgcn_mfma_f32_16x16x32_bf16(ah[mf], bh[nf], acc[mf][nf], 0, 0, 0);
                    acc[mf][nf] = __builtin_amdgcn_mfma_f32_16x16x32_bf16(ah[mf], bl[nf], acc[mf][nf], 0, 0, 0);
                    acc[mf][nf] = __builtin_amdgcn_mfma_f32_16x16x32_bf16(al[mf], bh[nf], acc[mf][nf], 0, 0, 0);
                }
            }
        }
    }

    // ---- epilogue: C/D layout col=lane&15, row=quad*4+reg ----
#pragma unroll
    for (int nf = 0; nf < 4; ++nf) {
        int col = o0 + wn + nf * 16 + l15;
        float bv = bias[i * LOUT + col];
#pragma unroll
        for (int mf = 0; mf < 4; ++mf) {
#pragma unroll
            for (int reg = 0; reg < 4; ++reg) {
                int row = b0 + wm + mf * 16 + quad * 4 + reg;
                out[(size_t)row * D_OUT + i * LOUT + col] = acc[mf][nf][reg] + bv;
            }
        }
    }
}

extern "C" void kernel_launch(void* const* d_in, const int* in_sizes, int n_in,
                              void* d_out, int out_size, void* d_ws, size_t ws_size,
                              hipStream_t stream) {
    float* x    = (float*)d_in[0];
    float* g0   = (float*)d_in[1];
    float* g1   = (float*)d_in[2];
    float* g2   = (float*)d_in[3];
    float* g3   = (float*)d_in[4];
    const float* bias = (const float*)d_in[5];
    float* out = (float*)d_out;
    float* ws = (float*)d_ws;

    float* xT   = ws + WS_XT;
    float* ghat = ws + WS_GHAT;
    float* S    = ws + WS_S;
    float* envT = ws + WS_ENVT;

    k_transpose<<<dim3(128, 64), dim3(32, 8), 0, stream>>>(x, xT);
    k_reduce_g<<<dim3(16, 8, 4), 256, 0, stream>>>(g0, g1, g2, g3, ghat);
    k_s<<<dim3(1024, 4), 256, 0, stream>>>(x, ghat, S);
    k_env<<<1024, 256, 0, stream>>>(S, envT);
    // in-place split AFTER the fp32 readers of G (stream-ordered)
    k_split_inplace<<<dim3(8192, 4), 256, 0, stream>>>(g0, g1, g2, g3);
    k_gemm_mfma<<<512, 256, 0, stream>>>((const unsigned char*)g0,
                                         (const unsigned char*)g1,
                                         (const unsigned char*)g2,
                                         (const unsigned char*)g3,
                                         xT, envT, bias, out);
}